// Round 16
// baseline (2833.844 us; speedup 1.0000x reference)
//
#include <hip/hip_runtime.h>

typedef short bf16x8 __attribute__((ext_vector_type(8)));
typedef float f32x4 __attribute__((ext_vector_type(4)));

#define AS 264            // plain layout; 528B row stride => <=2-way LDS aliasing (free)
#define T0OFF (32 * AS)
#define T1OFF (64 * AS)

__device__ __forceinline__ unsigned short f2bf(float f) {      // RNE (pre-kernels only)
    union { float f; unsigned int u; } v; v.f = f;
    unsigned int u = v.u + 0x7FFFu + ((v.u >> 16) & 1u);
    return (unsigned short)(u >> 16);
}
__device__ __forceinline__ unsigned pack2bf(float a, float b) { // [lo=a, hi=b]
    union { float f; unsigned u; } x, y; x.f = a; y.f = b;
    return ((x.u + 0x8000u) >> 16) | ((y.u + 0x8000u) & 0xffff0000u);
}
__device__ __forceinline__ float bf2f(unsigned int h) {
    union { unsigned int u; float f; } v; v.u = h << 16; return v.f;
}
__device__ __forceinline__ float sigm(float x) {
    return __builtin_amdgcn_rcpf(1.0f + __expf(-x));
}

struct f4s { float v[4]; };
__device__ __forceinline__ f4s ld4(const float* p) {
    float4 t = *(const float4*)p;
    f4s r; r.v[0] = t.x; r.v[1] = t.y; r.v[2] = t.z; r.v[3] = t.w; return r;
}

// ---------------- pre-kernels ----------------

__global__ void k_base(const float* __restrict__ ctx,
                       const float* __restrict__ w1,
                       const float* __restrict__ b1,
                       float* __restrict__ base) {
    const int b = blockIdx.x, n = threadIdx.x;
    float acc = b1[n];
    for (int c = 0; c < 128; ++c)
        acc += ctx[b * 128 + c] * w1[(3 + c) * 256 + n];
    base[b * 256 + n] = acc;
}

// wf[((kk*4+q)*256+n)*8+j] = bf16(W[kk*32+q*8+j][n])  — serves as the A(W^T) fragment
__global__ void k_frag(const float* __restrict__ w,
                       unsigned short* __restrict__ wf) {
    const int t = blockIdx.x * blockDim.x + threadIdx.x;  // 0..65535
    const int j = t & 7, n = (t >> 3) & 255, q = (t >> 11) & 3, kk = t >> 13;
    wf[t] = f2bf(w[(kk * 32 + q * 8 + j) * 256 + n]);
}

// ---------------- gemm: D = W^T · H  (W-frag as A operand, activations as B) ----------------
// Result C-layout: col = point (lane&15), row = n-in-block (q*4+r)  -> n-contiguous epilogue.
#define MFMA3(frag_base, buf)                                                              \
    {                                                                                      \
        const bf16x8 fP  = *(const bf16x8*)(Asl + (frag_base));                            \
        const bf16x8 fT0 = *(const bf16x8*)(Asl + (frag_base) + T0OFF);                    \
        const bf16x8 fT1 = *(const bf16x8*)(Asl + (frag_base) + T1OFF);                    \
        _Pragma("unroll")                                                                  \
        for (int nb = 0; nb < 4; ++nb) {                                                   \
            aP[nb]  = __builtin_amdgcn_mfma_f32_16x16x32_bf16(buf[nb], fP,  aP[nb],  0, 0, 0); \
            aT0[nb] = __builtin_amdgcn_mfma_f32_16x16x32_bf16(buf[nb], fT0, aT0[nb], 0, 0, 0); \
            aT1[nb] = __builtin_amdgcn_mfma_f32_16x16x32_bf16(buf[nb], fT1, aT1[nb], 0, 0, 0); \
        }                                                                                  \
    }

__device__ __forceinline__ void do_gemm_direct(const unsigned short* __restrict__ wf,
                                               const unsigned short* Asl,
                                               int raP, int base0,
                                               f32x4 aP[4], f32x4 aT0[4], f32x4 aT1[4]) {
    const bf16x8* __restrict__ wp = (const bf16x8*)wf;
    bf16x8 bufA[4], bufB[4];
#pragma unroll
    for (int nb = 0; nb < 4; ++nb) bufA[nb] = wp[base0 + nb * 16];
#pragma unroll 1
    for (int kk = 0; kk < 8; kk += 2) {
#pragma unroll
        for (int nb = 0; nb < 4; ++nb) bufB[nb] = wp[(kk + 1) * 1024 + base0 + nb * 16];
        MFMA3(raP + kk * 32, bufA);
        if (kk + 2 < 8) {
#pragma unroll
            for (int nb = 0; nb < 4; ++nb) bufA[nb] = wp[(kk + 2) * 1024 + base0 + nb * 16];
        }
        MFMA3(raP + (kk + 1) * 32, bufB);
    }
}

// epilogue: lane owns point=m, rows n = nb*16+q*4+(0..3) -> packed b64 stores (n-contiguous)
__device__ __forceinline__ void el_write(unsigned short* Asl,
                                         const f32x4* aP, const f32x4* aT0, const f32x4* aT1,
                                         int ebase) {
#pragma unroll
    for (int nb = 0; nb < 4; ++nb) {
        const int a = ebase + nb * 16;
        float hf[4], t0f[4], t1f[4];
#pragma unroll
        for (int r = 0; r < 4; ++r) {
            const float pre = aP[nb][r];            // bias already in acc
            const float s = sigm(pre);
            const float h = pre * s;
            const float d = fmaf(h, 1.0f - s, s);   // silu'(pre)
            hf[r]  = h;
            t0f[r] = d * aT0[nb][r];
            t1f[r] = d * aT1[nb][r];
        }
        uint2 vh, v0, v1;
        vh.x = pack2bf(hf[0],  hf[1]);  vh.y = pack2bf(hf[2],  hf[3]);
        v0.x = pack2bf(t0f[0], t0f[1]); v0.y = pack2bf(t0f[2], t0f[3]);
        v1.x = pack2bf(t1f[0], t1f[1]); v1.y = pack2bf(t1f[2], t1f[3]);
        *(uint2*)(Asl + a)          = vh;
        *(uint2*)(Asl + a + T0OFF)  = v0;
        *(uint2*)(Asl + a + T1OFF)  = v1;
    }
}

// ---------------- main kernel ----------------
// One WG = 32 points, 512 threads (8 waves), 2 WGs/CU.
// Waves: tw=wave&1 (point-tile), nbb=(wave>>1)*4 (4 N-blocks). Plain Asl [point][n].
__launch_bounds__(512, 4)
__global__ void k_main(const float* __restrict__ x,
                       const float* __restrict__ w1,
                       const float* __restrict__ b2g,
                       const float* __restrict__ b3g,
                       const float* __restrict__ w4g,
                       const float* __restrict__ b4g,
                       const unsigned short* __restrict__ w2f,
                       const unsigned short* __restrict__ w3f,
                       const float* __restrict__ basep,
                       float* __restrict__ ldacc,
                       float* __restrict__ out) {
    __shared__ unsigned short Asl[96 * AS];    // [h;t0;t1] bf16, plain (32 rows each)
    __shared__ float w1r[3][256];
    __shared__ float basel[256];
    __shared__ float w40[256], w41[256];
    __shared__ float b2l[256], b3l[256];
    __shared__ float ldl[32];

    const int tid = threadIdx.x;
    const int wg = blockIdx.x;
    const int b = wg >> 7;                // 128 WGs per batch
    const int n0 = (wg & 127) << 5;       // 32 points per WG

    for (int i = tid; i < 768; i += 512) w1r[i >> 8][i & 255] = w1[i];
    if (tid < 256) basel[tid] = basep[b * 256 + tid];
    if (tid < 256) { w40[tid] = w4g[2 * tid]; w41[tid] = w4g[2 * tid + 1]; }
    if (tid < 256) { b2l[tid] = b2g[tid]; b3l[tid] = b3g[tid]; }

    const int lane = tid & 63, wave = tid >> 6;
    const int m = lane & 15, q = lane >> 4;
    const int tw = wave & 1;                 // point-tile (16 points)
    const int nbb = (wave >> 1) << 2;        // N-block base: 0,4,8,12
    const int raPq  = (tw * 16 + m) * AS + q * 8;              // B(activation)-frag base
    const int ebase = (tw * 16 + m) * AS + nbb * 16 + q * 4;   // el_write base (n-contig)
    const int base0 = q * 256 + nbb * 16 + m;                  // W-frag bf16x8-unit base
    const int bq4 = q * 4;                                     // bias row base within block

    const int p4 = tid >> 4;            // point (0..31)
    const int ic = tid & 15;            // 16 threads per point

    // register-resident point state (replicated across the point's 16 lanes)
    float x0 = x[((b << 12) + n0 + p4) * 2];
    float x1 = x[((b << 12) + n0 + p4) * 2 + 1];
    float ldreg = 0.0f;
    const float b40 = b4g[0], b41 = b4g[1];
    __syncthreads();

#pragma unroll 1
    for (int st = 0; st < 10; ++st) {
        const float ti = 0.1f * (float)st;
        // ---------- layer 1 (fused with previous step's L4; registers only) ----------
#pragma unroll
        for (int g = 0; g < 4; ++g) {
            const int cb = (ic << 4) + g * 4;
            const f4s wa = ld4(&w1r[0][cb]);
            const f4s wb = ld4(&w1r[1][cb]);
            const f4s wc = ld4(&w1r[2][cb]);
            const f4s bs = ld4(&basel[cb]);
            float hf[4], t0f[4], t1f[4];
#pragma unroll
            for (int e = 0; e < 4; ++e) {
                const float pre = x0 * wa.v[e] + x1 * wb.v[e] + ti * wc.v[e] + bs.v[e];
                const float s = sigm(pre);
                const float h = pre * s;
                const float d = fmaf(h, 1.0f - s, s);
                hf[e]  = h;
                t0f[e] = d * wa.v[e];
                t1f[e] = d * wb.v[e];
            }
            uint2 v0, v1, v2;
            v0.x = pack2bf(hf[0],  hf[1]);  v0.y = pack2bf(hf[2],  hf[3]);
            v1.x = pack2bf(t0f[0], t0f[1]); v1.y = pack2bf(t0f[2], t0f[3]);
            v2.x = pack2bf(t1f[0], t1f[1]); v2.y = pack2bf(t1f[2], t1f[3]);
            *(uint2*)(Asl + p4 * AS + cb) = v0;
            *(uint2*)(Asl + T0OFF + p4 * AS + cb) = v1;
            *(uint2*)(Asl + T1OFF + p4 * AS + cb) = v2;
        }
        __syncthreads();

        // ---------- layer 2 ----------
        f32x4 aP[4], aT0[4], aT1[4];
#pragma unroll
        for (int i = 0; i < 4; ++i) {
            const f4s bs = ld4(&b2l[(nbb + i) * 16 + bq4]);
            aP[i]  = f32x4{bs.v[0], bs.v[1], bs.v[2], bs.v[3]};  // bias-seeded (rows = n)
            aT0[i] = f32x4{0.f, 0.f, 0.f, 0.f};
            aT1[i] = f32x4{0.f, 0.f, 0.f, 0.f};
        }
        do_gemm_direct(w2f, Asl, raPq, base0, aP, aT0, aT1);
        el_write(Asl, aP, aT0, aT1, ebase);
        __syncthreads();

        // ---------- layer 3 ----------
#pragma unroll
        for (int i = 0; i < 4; ++i) {
            const f4s bs = ld4(&b3l[(nbb + i) * 16 + bq4]);
            aP[i]  = f32x4{bs.v[0], bs.v[1], bs.v[2], bs.v[3]};
            aT0[i] = f32x4{0.f, 0.f, 0.f, 0.f};
            aT1[i] = f32x4{0.f, 0.f, 0.f, 0.f};
        }
        do_gemm_direct(w3f, Asl, raPq, base0, aP, aT0, aT1);
        el_write(Asl, aP, aT0, aT1, ebase);
        __syncthreads();

        // ---------- layer 4 + point update (registers; no trailing barrier) ----------
        {
            float v0 = 0.f, v1 = 0.f, j00 = 0.f, j11 = 0.f;
#pragma unroll
            for (int g = 0; g < 4; ++g) {
                const int cb = (ic << 4) + g * 4;
                const uint2 hv  = *(const uint2*)(Asl + p4 * AS + cb);
                const uint2 t0v = *(const uint2*)(Asl + T0OFF + p4 * AS + cb);
                const uint2 t1v = *(const uint2*)(Asl + T1OFF + p4 * AS + cb);
                const f4s wa = ld4(&w40[cb]);
                const f4s wb = ld4(&w41[cb]);
                const unsigned hu[4]  = { hv.x & 0xffffu,  hv.x >> 16,  hv.y & 0xffffu,  hv.y >> 16 };
                const unsigned t0u[4] = { t0v.x & 0xffffu, t0v.x >> 16, t0v.y & 0xffffu, t0v.y >> 16 };
                const unsigned t1u[4] = { t1v.x & 0xffffu, t1v.x >> 16, t1v.y & 0xffffu, t1v.y >> 16 };
#pragma unroll
                for (int e = 0; e < 4; ++e) {
                    const float h = bf2f(hu[e]);
                    v0  += h * wa.v[e];
                    v1  += h * wb.v[e];
                    j00 += bf2f(t0u[e]) * wa.v[e];
                    j11 += bf2f(t1u[e]) * wb.v[e];
                }
            }
#pragma unroll
            for (int o = 1; o < 16; o <<= 1) {   // butterfly across the point's 16 lanes
                v0  += __shfl_xor(v0, o);
                v1  += __shfl_xor(v1, o);
                j00 += __shfl_xor(j00, o);
                j11 += __shfl_xor(j11, o);
            }
            x0 += 0.1f * (v0 + b40);
            x1 += 0.1f * (v1 + b41);
            ldreg += 0.1f * (j00 + j11);
            // next L1 writes the same Asl addresses this thread just read: no barrier.
        }
    }

    // ---------- epilogue: FP32 output ----------
    if (ic == 0) {
        out[((b << 12) + n0 + p4) * 2]     = x0;
        out[((b << 12) + n0 + p4) * 2 + 1] = x1;
        ldl[p4] = ldreg;
    }
    __syncthreads();
    if (wave == 0) {
        float v = (lane < 32) ? ldl[lane] : 0.0f;
#pragma unroll
        for (int o = 32; o > 0; o >>= 1) v += __shfl_xor(v, o);
        if (lane == 0) atomicAdd(ldacc + b, v);
    }
}

// copy 64 float accumulators -> fp32 logdet outputs
__global__ void k_fin(const float* __restrict__ ldacc, float* __restrict__ out) {
    out[524288 + threadIdx.x] = ldacc[threadIdx.x];
}

extern "C" void kernel_launch(void* const* d_in, const int* in_sizes, int n_in,
                              void* d_out, int out_size, void* d_ws, size_t ws_size,
                              hipStream_t stream) {
    const float* x   = (const float*)d_in[0];
    const float* ctx = (const float*)d_in[1];
    const float* w1  = (const float*)d_in[2];
    const float* b1  = (const float*)d_in[3];
    const float* w2  = (const float*)d_in[4];
    const float* b2  = (const float*)d_in[5];
    const float* w3  = (const float*)d_in[6];
    const float* b3  = (const float*)d_in[7];
    const float* w4  = (const float*)d_in[8];
    const float* b4  = (const float*)d_in[9];

    // d_ws layout: [0,128K) w2f bf16 | [128K,256K) w3f bf16 | [256K,320K) base fp32 | [320K,+256) ldacc
    char* ws = (char*)d_ws;
    unsigned short* w2f = (unsigned short*)ws;
    unsigned short* w3f = (unsigned short*)(ws + 131072);
    float* basep = (float*)(ws + 262144);
    float* ldacc = (float*)(ws + 327680);
    float* out = (float*)d_out;

    hipMemsetAsync(ldacc, 0, 64 * sizeof(float), stream);
    k_base<<<dim3(64), dim3(256), 0, stream>>>(ctx, w1, b1, basep);
    k_frag<<<dim3(128), dim3(512), 0, stream>>>(w2, w2f);
    k_frag<<<dim3(128), dim3(512), 0, stream>>>(w3, w3f);
    k_main<<<dim3(8192), dim3(512), 0, stream>>>(x, w1, b2, b3, w4, b4, w2f, w3f, basep, ldacc, out);
    k_fin<<<dim3(1), dim3(64), 0, stream>>>(ldacc, out);
}